// Round 4
// baseline (1158.357 us; speedup 1.0000x reference)
//
#include <hip/hip_runtime.h>
#include <hip/hip_bf16.h>
#include <math.h>

// ---------------- problem constants ----------------
#define B_    512
#define DIM   128
#define A_    3
#define C_    200000
#define K_    50
#define DELTA 1e-3

typedef __attribute__((ext_vector_type(8))) short bf16x8;
typedef __attribute__((ext_vector_type(4))) float f32x4;

// ---------------- algorithm constants ----------------
#define NBIN_A 128          // 16 bins/octave over d2 in [16,4096)
#define CAP_A  1024
#define HSEG   16           // collect segments per (b,a) row
#define HSEGH  4            // hist segments per (b,a) row
#define CHPS   782          // 16B chunks per collect segment
#define CHPSH  3125         // 16B chunks per hist segment
#define ROWCH  12500        // 16B chunks per row (200000/16)
#define NL     16           // candidate slots per lane in select

// new gemm tiling
#define NSEG_G 196
#define TPS_G  8            // 196*8 = 1568 >= 1563
#define NT_G   1563
// fallback gemm tiling (round-3)
#define ONSEG  128
#define OTPS   13

// ---------------- ws layout (bytes) ----------------
#define OFF_H64   0u
#define OFF_HBF   524288u
#define OFF_Q2    655360u
#define OFF_HIST  657408u
#define OFF_CNT   1443840u
#define OFF_TAUB  1449984u
#define OFF_V64   1456128u
#define OFF_CAND  1468416u
#define OFF_BINS  7759872u
#define OFF_KBF   314959872u              // bins end 314,959,872 (fits proven 315.2MB)
#define OFF_K2    468559872u
#define NEED_F    470959872ull            // full path needs ~471 MB

static __device__ inline unsigned short f2bf(float x) {
    union { float f; unsigned u; } c; c.f = x;
    unsigned r = (c.u + 0x7FFFu + ((c.u >> 16) & 1u)) >> 16;
    return (unsigned short)r;
}
static __device__ inline unsigned pkbf(float a, float b) {
    __hip_bfloat162 t = __float22bfloat162_rn(make_float2(a, b));
    union { __hip_bfloat162 h; unsigned u; } cv; cv.h = t; return cv.u;
}

typedef __attribute__((address_space(1))) unsigned gu32_t;
typedef __attribute__((address_space(3))) unsigned lu32_t;
static __device__ inline void async_copy16(const void* g, void* l) {
    __builtin_amdgcn_global_load_lds((gu32_t*)g, (lu32_t*)l, 16, 0, 0);
}

// ============ MLP encoder (fp64, matches np-f64 ref) ============
__global__ __launch_bounds__(128) void mlp_kernel(
    const float* __restrict__ x,
    const float* __restrict__ W1, const float* __restrict__ b1,
    const float* __restrict__ W2, const float* __restrict__ b2,
    const float* __restrict__ W3, const float* __restrict__ b3,
    const float* __restrict__ W4, const float* __restrict__ b4,
    unsigned short* __restrict__ hbf, double* __restrict__ h64,
    float* __restrict__ q2)
{
    int b = blockIdx.x, t = threadIdx.x;
    __shared__ double s0[DIM], s1[DIM];
    double x0 = (double)x[b*2+0], x1 = (double)x[b*2+1];
    double h = x0*(double)W1[t] + x1*(double)W1[DIM+t] + (double)b1[t];
    s0[t] = h > 0.0 ? h : 0.0;
    __syncthreads();
    double acc = (double)b2[t];
    for (int k = 0; k < DIM; k++) acc += s0[k]*(double)W2[k*DIM+t];
    s1[t] = acc > 0.0 ? acc : 0.0;
    __syncthreads();
    acc = (double)b3[t];
    for (int k = 0; k < DIM; k++) acc += s1[k]*(double)W3[k*DIM+t];
    s0[t] = acc > 0.0 ? acc : 0.0;
    __syncthreads();
    acc = (double)b4[t];
    for (int k = 0; k < DIM; k++) acc += s0[k]*(double)W4[k*DIM+t];
    h64[b*DIM+t] = acc;
    float hf = (float)acc;
    hbf[b*DIM+t] = f2bf(hf);
    s1[t] = acc*acc;
    __syncthreads();
    for (int s = 64; s > 0; s >>= 1) { if (t < s) s1[t] += s1[t+s]; __syncthreads(); }
    if (t == 0) q2[b] = (float)s1[0];
}

// ============ convert keys fp32 -> bf16 + k2 (stream) ============
// 16 lanes per row; lane loads 8 floats (32B), packs 8 bf16 (16B).
__global__ __launch_bounds__(256) void convert_kernel(
    const float* __restrict__ keys, unsigned short* __restrict__ kbf,
    float* __restrict__ k2)
{
    int row = blockIdx.x*16 + (threadIdx.x >> 4);
    int t = threadIdx.x & 15;
    const float4* src = (const float4*)(keys + (size_t)row*DIM);
    float4 v0 = src[t*2], v1 = src[t*2+1];
    float ss = v0.x*v0.x + v0.y*v0.y + v0.z*v0.z + v0.w*v0.w
             + v1.x*v1.x + v1.y*v1.y + v1.z*v1.z + v1.w*v1.w;
    int4 pk;
    pk.x = (int)pkbf(v0.x, v0.y); pk.y = (int)pkbf(v0.z, v0.w);
    pk.z = (int)pkbf(v1.x, v1.y); pk.w = (int)pkbf(v1.z, v1.w);
    ((int4*)kbf)[(size_t)row*16 + t] = pk;
    #pragma unroll
    for (int off = 8; off > 0; off >>= 1) ss += __shfl_xor(ss, off, 16);
    if (t == 0) k2[row] = ss;
}

// ============ full path: bf16 MFMA distance GEMM -> u8 log-bins ============
// A = keys (rows n), B = h (cols b). Staging via global_load_lds (16B) with
// XOR source-swizzle: LDS chunk c_phys of row r holds logical chunk
// c_phys ^ (r&15). Unpadded 256B rows; fragment reads are bank-balanced.
__global__ __launch_bounds__(256, 2) void gemm_bin_kernel(
    const unsigned short* __restrict__ kbf, const float* __restrict__ k2,
    const unsigned short* __restrict__ hbf, const float* __restrict__ q2,
    unsigned char* __restrict__ bins)
{
    const int seg = blockIdx.x, my = blockIdx.y, a = blockIdx.z;
    const int b0 = my*128;
    const int tid = threadIdx.x;
    const int lane = tid & 63, w = tid >> 6;
    const int lm = lane & 15, kh = lane >> 4;
    const int wm = w & 1;        // n half
    const int wn = w >> 1;       // b half

    __shared__ unsigned short sA[128*128];   // keys bf16, swizzled chunks
    __shared__ unsigned short sB[128*128];   // h bf16, swizzled chunks
    __shared__ float q2s[128];

    // stage h once (swizzled ds_write)
    {
        int r = tid >> 1, hh = tid & 1;
        const int4* gp = (const int4*)hbf + (size_t)(b0 + r)*16;
        #pragma unroll
        for (int q = 0; q < 8; q++) {
            int c = hh*8 + q;
            int phys = c ^ (r & 15);
            *(int4*)&sB[r*128 + phys*8] = gp[c];
        }
        if (tid < 128) q2s[tid] = q2[b0 + tid];
    }

    // precompute per-lane async-staging source pointers (8 segments of 4 rows)
    const char* gp8[8];
    const int srow = lane >> 4;       // row within 4-row segment
    const int sphys = lane & 15;      // physical chunk = lane&15
    {
        const char* kbase = (const char*)kbf
            + ((size_t)a*C_ + (size_t)seg*TPS_G*128)*256;
        #pragma unroll
        for (int q = 0; q < 8; q++) {
            int s = w*8 + q;
            int row_q = s*4 + srow;
            int lc = sphys ^ (row_q & 15);
            gp8[q] = kbase + (size_t)row_q*256 + lc*16;
        }
    }
    const int kstx = lm >> 2;
    const int khx  = kh ^ (lm & 3);
    const float* __restrict__ k2g = k2 + (size_t)a*C_;

    for (int t = 0; t < TPS_G; t++) {
        int nt = seg*TPS_G + t;
        if (nt >= NT_G) break;
        int n0 = nt*128;
        __syncthreads();   // prev tile's LDS reads done (also covers sB stage)
        #pragma unroll
        for (int q = 0; q < 8; q++) {
            async_copy16(gp8[q], &sA[(w*8 + q)*512]);
            gp8[q] += 128*256;
        }
        __syncthreads();   // vmcnt(0) drain: sA filled

        f32x4 acc[4][4];
        #pragma unroll
        for (int i = 0; i < 4; i++)
            #pragma unroll
            for (int j = 0; j < 4; j++) acc[i][j] = (f32x4){0.f, 0.f, 0.f, 0.f};

        #pragma unroll
        for (int kst = 0; kst < 4; kst++) {
            int pc8 = (4*(kst ^ kstx) + khx) * 8;   // swizzled chunk offset (shorts)
            bf16x8 af[4], bfv[4];
            #pragma unroll
            for (int i = 0; i < 4; i++)
                af[i] = *(const bf16x8*)&sA[(wm*64 + i*16 + lm)*128 + pc8];
            #pragma unroll
            for (int j = 0; j < 4; j++)
                bfv[j] = *(const bf16x8*)&sB[(wn*64 + j*16 + lm)*128 + pc8];
            #pragma unroll
            for (int i = 0; i < 4; i++)
                #pragma unroll
                for (int j = 0; j < 4; j++)
                    acc[i][j] = __builtin_amdgcn_mfma_f32_16x16x32_bf16(af[i], bfv[j], acc[i][j], 0, 0, 0);
        }

        // epilogue: d2 = q2[b] + k2[n] - 2*cross -> u8 bins packed as dwords
        float qv[4];
        #pragma unroll
        for (int j = 0; j < 4; j++) qv[j] = q2s[wn*64 + j*16 + lm];
        #pragma unroll
        for (int i = 0; i < 4; i++) {
            int nb = wm*64 + i*16 + kh*4;
            int n  = n0 + nb;
            if (n < C_) {                      // C_%4==0 -> full dword valid
                float4 kb = *(const float4*)(k2g + n);
                #pragma unroll
                for (int j = 0; j < 4; j++) {
                    int bl = wn*64 + j*16 + lm;
                    unsigned pk = 0;
                    #pragma unroll
                    for (int r = 0; r < 4; r++) {
                        float kr = (r==0 ? kb.x : r==1 ? kb.y : r==2 ? kb.z : kb.w);
                        float d2v = fmaf(-2.0f, acc[i][j][r], qv[j] + kr);
                        float dc  = fminf(fmaxf(d2v, 16.0f), 4095.0f);
                        unsigned u = (__float_as_uint(dc) >> 19) - 2096u;
                        pk |= u << (8*r);
                    }
                    *(unsigned*)(bins + ((size_t)(a*B_ + b0 + bl))*C_ + n) = pk;
                }
            }
        }
    }
}

// ============ fallback gemm (round-3, fp32 keys in-kernel) ============
__global__ __launch_bounds__(256, 2) void gemm_bin_old(
    const float* __restrict__ keys, const unsigned short* __restrict__ hbf,
    const float* __restrict__ q2, unsigned char* __restrict__ bins)
{
    const int seg = blockIdx.x, my = blockIdx.y, a = blockIdx.z;
    const int b0 = my*128;
    const int tid = threadIdx.x;
    const int lane = tid & 63, w = tid >> 6;
    const int lm = lane & 15, kh = lane >> 4;
    const int wm = w & 1, wn = w >> 1;

    __shared__ short sA[128*136];
    __shared__ short sB[128*136];
    __shared__ __align__(16) float q2s[128];
    __shared__ __align__(16) float k2s[128];

    {
        int r = tid >> 1, hh = tid & 1;
        const int4* gp = (const int4*)hbf + (size_t)(b0 + r)*16 + hh*8;
        int4* dp = (int4*)&sB[r*136 + hh*64];
        #pragma unroll
        for (int q = 0; q < 8; q++) dp[q] = gp[q];
        if (tid < 128) q2s[tid] = q2[b0 + tid];
    }

    for (int t = 0; t < OTPS; t++) {
        int nt = seg*OTPS + t;
        if (nt >= NT_G) break;
        int n0 = nt*128;
        __syncthreads();
        {
            int r = tid >> 1, hh = tid & 1;
            int nr = n0 + r; if (nr >= C_) nr = C_-1;
            const float4* gp = (const float4*)(keys + ((size_t)a*C_ + nr)*128) + hh*16;
            float ss = 0.0f;
            int4* dp = (int4*)&sA[r*136 + hh*64];
            #pragma unroll
            for (int q = 0; q < 8; q++) {
                float4 v0 = gp[2*q], v1 = gp[2*q+1];
                ss += v0.x*v0.x + v0.y*v0.y + v0.z*v0.z + v0.w*v0.w
                    + v1.x*v1.x + v1.y*v1.y + v1.z*v1.z + v1.w*v1.w;
                int4 pk;
                pk.x = (int)pkbf(v0.x, v0.y);
                pk.y = (int)pkbf(v0.z, v0.w);
                pk.z = (int)pkbf(v1.x, v1.y);
                pk.w = (int)pkbf(v1.z, v1.w);
                dp[q] = pk;
            }
            ss += __shfl_xor(ss, 1, 64);
            if (hh == 0) k2s[r] = ss;
        }
        __syncthreads();

        f32x4 acc[4][4];
        #pragma unroll
        for (int i = 0; i < 4; i++)
            #pragma unroll
            for (int j = 0; j < 4; j++) acc[i][j] = (f32x4){0.f, 0.f, 0.f, 0.f};

        #pragma unroll
        for (int kst = 0; kst < 4; kst++) {
            bf16x8 af[4], bfv[4];
            #pragma unroll
            for (int i = 0; i < 4; i++)
                af[i] = *(const bf16x8*)&sA[(wm*64 + i*16 + lm)*136 + kst*32 + kh*8];
            #pragma unroll
            for (int j = 0; j < 4; j++)
                bfv[j] = *(const bf16x8*)&sB[(wn*64 + j*16 + lm)*136 + kst*32 + kh*8];
            #pragma unroll
            for (int i = 0; i < 4; i++)
                #pragma unroll
                for (int j = 0; j < 4; j++)
                    acc[i][j] = __builtin_amdgcn_mfma_f32_16x16x32_bf16(af[i], bfv[j], acc[i][j], 0, 0, 0);
        }

        float qv[4];
        #pragma unroll
        for (int j = 0; j < 4; j++) qv[j] = q2s[wn*64 + j*16 + lm];
        #pragma unroll
        for (int i = 0; i < 4; i++) {
            int nb = wm*64 + i*16 + kh*4;
            int n  = n0 + nb;
            float4 kb = *(const float4*)&k2s[nb];
            if (n < C_) {
                #pragma unroll
                for (int j = 0; j < 4; j++) {
                    int bl = wn*64 + j*16 + lm;
                    unsigned pk = 0;
                    #pragma unroll
                    for (int r = 0; r < 4; r++) {
                        float kr = (r==0 ? kb.x : r==1 ? kb.y : r==2 ? kb.z : kb.w);
                        float d2v = fmaf(-2.0f, acc[i][j][r], qv[j] + kr);
                        float dc  = fminf(fmaxf(d2v, 16.0f), 4095.0f);
                        unsigned u = (__float_as_uint(dc) >> 19) - 2096u;
                        pk |= u << (8*r);
                    }
                    *(unsigned*)(bins + ((size_t)(a*B_ + b0 + bl))*C_ + n) = pk;
                }
            }
        }
    }
}

// ============ histogram: private per-thread u8 rows, no atomics ============
// hs[tid][pos] with pos = bin ^ ((tid&31)*4): bank = (bin>>2)^(tid&31) ->
// conflict-free for clustered bins. Reduce via packed u16 halves.
__global__ __launch_bounds__(256) void histA_kernel(const unsigned char* __restrict__ bins,
                                                    unsigned* __restrict__ hist)
{
    int q = blockIdx.x;            // a*B_ + b
    int seg = blockIdx.y;
    int tid = threadIdx.x;
    int a = q >> 9, b = q & 511;
    int p = b*A_ + a;
    __shared__ unsigned hs32[256*32];   // 32 kB: per-thread 128 u8 bins
    __shared__ unsigned plo[256], phi[256];
    unsigned char* hs8 = (unsigned char*)hs32;
    #pragma unroll
    for (int i = 0; i < 32; i++) hs32[tid*32 + i] = 0;
    __syncthreads();

    const uint4* row = (const uint4*)(bins + (size_t)q*C_);
    int ch0 = seg*CHPSH, ch1 = ch0 + CHPSH; if (ch1 > ROWCH) ch1 = ROWCH;
    unsigned swz = (unsigned)((tid & 31) << 2);
    unsigned base = (unsigned)tid << 7;
    for (int ch = ch0 + tid; ch < ch1; ch += 256) {
        uint4 v = row[ch];
        unsigned d[4] = {v.x, v.y, v.z, v.w};
        #pragma unroll
        for (int e = 0; e < 4; e++) {
            unsigned x = d[e];
            hs8[base + (((x      ) & 127u) ^ swz)]++;
            hs8[base + (((x >>  8) & 127u) ^ swz)]++;
            hs8[base + (((x >> 16) & 127u) ^ swz)]++;
            hs8[base + (((x >> 24) & 127u) ^ swz)]++;
        }
    }
    __syncthreads();

    // stage 1: thread (j = tid&31 logical quad, s = tid>>5 row-range)
    {
        int j = tid & 31, s = tid >> 5;
        unsigned lo = 0, hi = 0;
        #pragma unroll 4
        for (int m = 0; m < 32; m++) {
            unsigned v = hs32[(s*32 + m)*32 + (j ^ m)];
            lo += v & 0x00FF00FFu;
            hi += (v >> 8) & 0x00FF00FFu;
        }
        plo[tid] = lo; phi[tid] = hi;
    }
    __syncthreads();
    if (tid < 32) {
        int j = tid;
        unsigned L = 0, H = 0;
        #pragma unroll
        for (int s = 0; s < 8; s++) { L += plo[s*32 + j]; H += phi[s*32 + j]; }
        unsigned* hp = hist + (size_t)p*NBIN_A + 4*j;
        unsigned c0 = L & 0xFFFFu, c1 = H & 0xFFFFu, c2 = L >> 16, c3 = H >> 16;
        if (c0) atomicAdd(hp + 0, c0);
        if (c1) atomicAdd(hp + 1, c1);
        if (c2) atomicAdd(hp + 2, c2);
        if (c3) atomicAdd(hp + 3, c3);
    }
}

// ============ threshold bin ============
__global__ void tauA_kernel(const unsigned* __restrict__ hist, int* __restrict__ taubin)
{
    int p = blockIdx.x*256 + threadIdx.x;
    if (p >= B_*A_) return;
    const unsigned* hp = hist + (size_t)p*NBIN_A;
    unsigned cum = 0; int jsel = NBIN_A-1;
    for (int j = 0; j < NBIN_A; j++) { cum += hp[j]; if (cum >= K_) { jsel = j; break; } }
    unsigned c1 = cum + (jsel+1 < NBIN_A ? hp[jsel+1] : 0u);
    unsigned c2 = c1  + (jsel+2 < NBIN_A ? hp[jsel+2] : 0u);
    int jt = (c2 <= 768u) ? jsel+2 : jsel+1;
    if (jt > NBIN_A-1) jt = NBIN_A-1;
    taubin[p] = jt;
}

// ============ streaming candidate collect ============
__global__ __launch_bounds__(256) void collectA_kernel(const unsigned char* __restrict__ bins,
    const int* __restrict__ taubin, unsigned* __restrict__ cnt, int* __restrict__ cand)
{
    int q = blockIdx.x, seg = blockIdx.y, tid = threadIdx.x;
    int a = q >> 9, b = q & 511;
    int p = b*A_ + a;
    int tb = taubin[p];
    unsigned thr  = (unsigned)(tb + 1);
    unsigned addv = (128u - thr) * 0x01010101u;
    const uint4* row = (const uint4*)(bins + (size_t)q*C_);
    int ch0 = seg*CHPS, ch1 = ch0 + CHPS; if (ch1 > ROWCH) ch1 = ROWCH;
    for (int ch = ch0 + tid; ch < ch1; ch += 256) {
        uint4 v = row[ch];
        unsigned d[4] = {v.x, v.y, v.z, v.w};
        #pragma unroll
        for (int e = 0; e < 4; e++) {
            unsigned m = (d[e] + addv) & 0x80808080u;
            if (m != 0x80808080u) {
                #pragma unroll
                for (int by = 0; by < 4; by++) {
                    if (!((m >> (8*by + 7)) & 1u)) {
                        int n = ch*16 + e*4 + by;
                        unsigned pos = atomicAdd(&cnt[p], 1u);
                        if (pos < CAP_A) cand[(size_t)p*CAP_A + pos] = n;
                    }
                }
            }
        }
    }
}

// ============ exact fp64 top-K, one wave per (b,a) ============
__global__ __launch_bounds__(64) void select_kernel(
    const float* __restrict__ keys, const double* __restrict__ h64,
    const float* __restrict__ mem_values,
    const unsigned* __restrict__ cnt, const int* __restrict__ cand,
    float* __restrict__ out_values, double* __restrict__ val64)
{
    int p = blockIdx.x; int b = p / A_, a = p % A_;
    int lane = threadIdx.x;
    __shared__ double hd[DIM];
    __shared__ float  vsm[CAP_A];

    for (int i = lane; i < DIM; i += 64) hd[i] = h64[(size_t)b*DIM + i];
    int n = (int)cnt[p]; if (n > CAP_A) n = CAP_A;
    __syncthreads();

    double d2r[NL];
    #pragma unroll
    for (int s = 0; s < NL; s++) d2r[s] = 1e300;

    #pragma unroll 1
    for (int s = 0; s < NL; s++) {
        int i = s*64 + lane;
        if (i < n) {
            int c = cand[(size_t)p*CAP_A + i];
            const float4* kr = (const float4*)(keys + ((size_t)a*C_ + c)*DIM);
            double s0 = 0.0, s1 = 0.0;
            #pragma unroll 4
            for (int kq = 0; kq < 32; kq++) {
                float4 kv = kr[kq];
                double d0 = hd[4*kq+0] - (double)kv.x;
                double d1 = hd[4*kq+1] - (double)kv.y;
                double d2 = hd[4*kq+2] - (double)kv.z;
                double d3 = hd[4*kq+3] - (double)kv.w;
                s0 += d0*d0 + d1*d1; s1 += d2*d2 + d3*d3;
            }
            double d = s0 + s1;
            unsigned long long bits = __double_as_longlong(d);
            bits = (bits & ~1023ull) | (unsigned long long)i;
            d2r[s] = __longlong_as_double(bits);
            vsm[i] = mem_values[(size_t)a*C_ + c];
        }
    }
    __syncthreads();

    double accw = 0.0, accwv = 0.0;
    for (int t = 0; t < K_; t++) {
        double best = d2r[0];
        #pragma unroll
        for (int s = 1; s < NL; s++) best = fmin(best, d2r[s]);
        #pragma unroll
        for (int off = 32; off > 0; off >>= 1) {
            double o = __shfl_xor(best, off, 64);
            best = fmin(best, o);
        }
        if (best >= 1e300) break;
        unsigned gidx = (unsigned)(__double_as_longlong(best) & 1023ull);
        int ol = gidx & 63, os = gidx >> 6;
        if (lane == ol) {
            #pragma unroll
            for (int s = 0; s < NL; s++) if (s == os) d2r[s] = 1e300;
        }
        double d = best; if (d < 0.0) d = 0.0;
        double wgt = 1.0 / (d + DELTA);
        accw += wgt; accwv += wgt * (double)vsm[gidx];
    }
    if (lane == 0) {
        double v = accwv / accw;
        out_values[p] = (float)v;
        val64[p] = v;
    }
}

__global__ void argmax_kernel(const double* __restrict__ val64, float* __restrict__ out)
{
    int b = blockIdx.x*blockDim.x + threadIdx.x;
    if (b >= B_) return;
    double v0 = val64[b*A_+0], v1 = val64[b*A_+1], v2 = val64[b*A_+2];
    int bi = 0; double bv = v0;
    if (v1 > bv) { bv = v1; bi = 1; }
    if (v2 > bv) { bv = v2; bi = 2; }
    out[B_*A_ + b] = (float)bi;
}

// ============ host ============
extern "C" void kernel_launch(void* const* d_in, const int* in_sizes, int n_in,
                              void* d_out, int out_size, void* d_ws, size_t ws_size,
                              hipStream_t stream)
{
    const float* x    = (const float*)d_in[0];
    const float* W1   = (const float*)d_in[1];
    const float* b1   = (const float*)d_in[2];
    const float* W2   = (const float*)d_in[3];
    const float* b2   = (const float*)d_in[4];
    const float* W3   = (const float*)d_in[5];
    const float* b3   = (const float*)d_in[6];
    const float* W4   = (const float*)d_in[7];
    const float* b4   = (const float*)d_in[8];
    const float* keys = (const float*)d_in[9];
    const float* memv = (const float*)d_in[10];

    char* ws = (char*)d_ws;
    double*         h64  = (double*)        (ws + OFF_H64);
    unsigned short* hbf  = (unsigned short*)(ws + OFF_HBF);
    float*          q2   = (float*)         (ws + OFF_Q2);
    unsigned*       hist = (unsigned*)      (ws + OFF_HIST);
    unsigned*       cnt  = (unsigned*)      (ws + OFF_CNT);
    int*            taub = (int*)           (ws + OFF_TAUB);
    double*         v64  = (double*)        (ws + OFF_V64);
    int*            cand = (int*)           (ws + OFF_CAND);
    unsigned char*  bins = (unsigned char*) (ws + OFF_BINS);
    unsigned short* kbf  = (unsigned short*)(ws + OFF_KBF);
    float*          k2   = (float*)         (ws + OFF_K2);

    hipMemsetAsync(ws + OFF_HIST, 0, (OFF_CNT + B_*A_*4) - OFF_HIST, stream);

    mlp_kernel<<<B_, 128, 0, stream>>>(x, W1, b1, W2, b2, W3, b3, W4, b4, hbf, h64, q2);

    if (ws_size >= NEED_F) {
        convert_kernel<<<(A_*C_)/16, 256, 0, stream>>>(keys, kbf, k2);
        gemm_bin_kernel<<<dim3(NSEG_G, 4, A_), 256, 0, stream>>>(kbf, k2, hbf, q2, bins);
    } else {
        gemm_bin_old<<<dim3(ONSEG, 4, A_), 256, 0, stream>>>(keys, hbf, q2, bins);
    }

    histA_kernel<<<dim3(B_*A_, HSEGH), 256, 0, stream>>>(bins, hist);
    tauA_kernel<<<(B_*A_ + 255)/256, 256, 0, stream>>>(hist, taub);
    collectA_kernel<<<dim3(B_*A_, HSEG), 256, 0, stream>>>(bins, taub, cnt, cand);
    select_kernel<<<B_*A_, 64, 0, stream>>>(keys, h64, memv, cnt, cand, (float*)d_out, v64);
    argmax_kernel<<<2, 256, 0, stream>>>(v64, (float*)d_out);
}